// Round 9
// baseline (177.794 us; speedup 1.0000x reference)
//
#include <hip/hip_runtime.h>
#include <stdint.h>

// Problem constants (from reference)
#define B_SZ   512
#define T_SZ   100
#define NPRE   256
#define NPOST  256
#define KTOT   (B_SZ * T_SZ)   // 51200

typedef __bf16 bf16x8 __attribute__((ext_vector_type(8)));
typedef float  floatx4 __attribute__((ext_vector_type(4)));

__device__ __forceinline__ uint32_t bf16_rne(float v) {
    uint32_t bits = __float_as_uint(v);
    return (bits + 0x7FFFu + ((bits >> 16) & 1u)) >> 16;
}
__device__ __forceinline__ uint32_t pack_trunc2(float a, float b) {
    return (__float_as_uint(a) >> 16) | (__float_as_uint(b) & 0xFFFF0000u);
}

// ---------------------------------------------------------------------------
// Fused scan+GEMM: 256 blocks x 512 thr; s = bx&127 (batches 4s..4s+3),
// pt = bx>>7 (p-tile).  LDS = A 32 KB + B 32 KB = 64 KB -> 2 blocks/CU
// (16 waves/CU) so one block's barrier drain overlaps the other block's
// loads/MFMA (m114 co-scheduling) — R8 was 1 block/CU and 85% wait.
//
// Phase A (once): thread tid scans pre for (b = 4s + tid>>7,
// p = pt*128 + (tid&127)) — flat batched coalesced loads, fp32 carry,
// RNE->bf16, packed pairs in 50 VGPRs.
// Phase B (per batch lb, two half-K sub-phases):
//   sub 0: quarter-group lb deposits A_lds; all stage post t 0..63 -> B_lds;
//          sync; MFMA kc 0,1; sync.
//   sub 1: stage post t 64..99 (+pad) -> B_lds; sync; MFMA kc 2,3; sync.
// ---------------------------------------------------------------------------
__global__ __launch_bounds__(512, 4) void stdp_fused_gemm(
    const float* __restrict__ pre, const float* __restrict__ post,
    float* __restrict__ partial)
{
    __shared__ __align__(16) unsigned short A_lds[32][512];  // 32 KB
    __shared__ __align__(16) unsigned short B_lds[32][512];  // 32 KB

    const int bx = blockIdx.x;        // 0..255
    const int s  = bx & 127;          // K-split
    const int pt = bx >> 7;           // p-tile
    const int tid = threadIdx.x;
    const int lane = tid & 63, wave = tid >> 6;
    const int wp = wave & 3, wq = wave >> 2;
    const int l15 = lane & 15, l4 = lane >> 4;

    // ---- Phase A: per-thread trace scan (batch 4s+lbo, pre-neuron p) ----
    const int p_loc = tid & 127, lbo = tid >> 7;   // lbo is wave-uniform
    uint32_t pk[50];                               // bf16 pairs, t = 0..99
    {
        const int b = s * 4 + lbo;
        const float decay = 0.95122942450071400910f;  // expf(-1/20)
        const float* src = pre + (size_t)b * (T_SZ * NPRE) + pt * 128 + p_loc;
        float carry = 0.0f;
#pragma unroll
        for (int kc = 0; kc < 3; ++kc) {
            float x[32];
#pragma unroll
            for (int j = 0; j < 32; ++j)
                x[j] = src[(size_t)(kc * 32 + j) * NPRE];
#pragma unroll
            for (int j = 0; j < 16; ++j) {
                uint32_t lo = bf16_rne(carry);   // trace[t]=carry, then update
                carry = decay * (carry + x[2 * j]);
                uint32_t hi = bf16_rne(carry);
                carry = decay * (carry + x[2 * j + 1]);
                pk[kc * 16 + j] = lo | (hi << 16);
            }
        }
        float x[4];
#pragma unroll
        for (int j = 0; j < 4; ++j)
            x[j] = src[(size_t)(96 + j) * NPRE];
#pragma unroll
        for (int j = 0; j < 2; ++j) {
            uint32_t lo = bf16_rne(carry);
            carry = decay * (carry + x[2 * j]);
            uint32_t hi = bf16_rne(carry);
            carry = decay * (carry + x[2 * j + 1]);
            pk[48 + j] = lo | (hi << 16);
        }
    }

    // ---- Phase B ----
    const int q = tid & 255, hh = tid >> 8;   // staging role (wave-uniform hh)
    const int qg = q >> 4, q15 = q & 15;

    floatx4 acc[2][8] = {};

    for (int lb = 0; lb < 4; ++lb) {
        const int b = s * 4 + lb;
        const float* pb = post + (size_t)b * (T_SZ * NPOST) + q;

        // ===== sub-phase 0: A deposit + B stage t 0..63 =====
        if (lbo == lb) {
            const int pg = p_loc >> 4, lp = p_loc & 15;
#pragma unroll
            for (int kc = 0; kc < 3; ++kc)
#pragma unroll
                for (int l4w = 0; l4w < 4; ++l4w)
                    *(uint4*)&A_lds[kc * 8 + pg][(l4w * 16 + lp) * 8] =
                        make_uint4(pk[kc * 16 + l4w * 4], pk[kc * 16 + l4w * 4 + 1],
                                   pk[kc * 16 + l4w * 4 + 2], pk[kc * 16 + l4w * 4 + 3]);
            // kc = 3: t 96..99 real, 100..127 zero
            *(uint4*)&A_lds[24 + pg][lp * 8] = make_uint4(pk[48], pk[49], 0u, 0u);
#pragma unroll
            for (int l4w = 1; l4w < 4; ++l4w)
                *(uint4*)&A_lds[24 + pg][(l4w * 16 + lp) * 8] =
                    make_uint4(0u, 0u, 0u, 0u);
        }
        {
            // t-range hh*32 .. +31 -> B_lds line hh*16+qg, slot o*16+q15
            float x[32];
#pragma unroll
            for (int j = 0; j < 32; ++j)
                x[j] = pb[(size_t)(hh * 32 + j) * NPOST];
#pragma unroll
            for (int o = 0; o < 4; ++o)
                *(uint4*)&B_lds[hh * 16 + qg][(o * 16 + q15) * 8] =
                    make_uint4(pack_trunc2(x[o * 8 + 0], x[o * 8 + 1]),
                               pack_trunc2(x[o * 8 + 2], x[o * 8 + 3]),
                               pack_trunc2(x[o * 8 + 4], x[o * 8 + 5]),
                               pack_trunc2(x[o * 8 + 6], x[o * 8 + 7]));
        }
        __syncthreads();
#pragma unroll
        for (int kc = 0; kc < 2; ++kc) {
            bf16x8 a[2], bb[8];
#pragma unroll
            for (int f = 0; f < 2; ++f)
                a[f] = *(const bf16x8*)&A_lds[kc * 8 + wp * 2 + f][lane * 8];
#pragma unroll
            for (int g = 0; g < 8; ++g)
                bb[g] = *(const bf16x8*)&B_lds[kc * 16 + wq * 8 + g][lane * 8];
#pragma unroll
            for (int f = 0; f < 2; ++f)
#pragma unroll
                for (int g = 0; g < 8; ++g)
                    acc[f][g] = __builtin_amdgcn_mfma_f32_16x16x32_bf16(
                        a[f], bb[g], acc[f][g], 0, 0, 0);
        }
        __syncthreads();

        // ===== sub-phase 1: B stage t 64..127(pad) =====
        if (hh == 0) {
            // t 64..95 -> line qg (kcLocal 0)
            float x[32];
#pragma unroll
            for (int j = 0; j < 32; ++j)
                x[j] = pb[(size_t)(64 + j) * NPOST];
#pragma unroll
            for (int o = 0; o < 4; ++o)
                *(uint4*)&B_lds[qg][(o * 16 + q15) * 8] =
                    make_uint4(pack_trunc2(x[o * 8 + 0], x[o * 8 + 1]),
                               pack_trunc2(x[o * 8 + 2], x[o * 8 + 3]),
                               pack_trunc2(x[o * 8 + 4], x[o * 8 + 5]),
                               pack_trunc2(x[o * 8 + 6], x[o * 8 + 7]));
        } else {
            // t 96..99 real + zeros -> line 16+qg (kcLocal 1)
            float y[4];
#pragma unroll
            for (int j = 0; j < 4; ++j)
                y[j] = pb[(size_t)(96 + j) * NPOST];
            *(uint4*)&B_lds[16 + qg][(q15) * 8] =
                make_uint4(pack_trunc2(y[0], y[1]), pack_trunc2(y[2], y[3]), 0u, 0u);
#pragma unroll
            for (int o = 1; o < 4; ++o)
                *(uint4*)&B_lds[16 + qg][(o * 16 + q15) * 8] =
                    make_uint4(0u, 0u, 0u, 0u);
        }
        __syncthreads();
#pragma unroll
        for (int kc = 0; kc < 2; ++kc) {
            bf16x8 a[2], bb[8];
#pragma unroll
            for (int f = 0; f < 2; ++f)
                a[f] = *(const bf16x8*)&A_lds[(kc + 2) * 8 + wp * 2 + f][lane * 8];
#pragma unroll
            for (int g = 0; g < 8; ++g)
                bb[g] = *(const bf16x8*)&B_lds[kc * 16 + wq * 8 + g][lane * 8];
#pragma unroll
            for (int f = 0; f < 2; ++f)
#pragma unroll
                for (int g = 0; g < 8; ++g)
                    acc[f][g] = __builtin_amdgcn_mfma_f32_16x16x32_bf16(
                        a[f], bb[g], acc[f][g], 0, 0, 0);
        }
        __syncthreads();
    }

    // ---- writeout: partial[bx][p_loc 128][q 256]
    // C/D layout (m89/m91): col = lane&15, row = (lane>>4)*4 + reg
    float* pout = partial + (size_t)bx * (128 * 256);
#pragma unroll
    for (int f = 0; f < 2; ++f) {
        int r0 = wp * 32 + f * 16 + l4 * 4;
#pragma unroll
        for (int g = 0; g < 8; ++g) {
            int c = wq * 128 + g * 16 + l15;
#pragma unroll
            for (int v = 0; v < 4; ++v)
                pout[(size_t)(r0 + v) * 256 + c] = acc[f][g][v];
        }
    }
}

// ---------------------------------------------------------------------------
// Reduce stage 1: partial[bx = pt*128+s][i], i = p_loc*256+q.
// 2048 blocks x 256 thr; thread t: g = t>>16 (0..7), e = t&65535,
// pt = e>>15; sums s = g*16 .. g*16+15 (4 indep chains).
// ---------------------------------------------------------------------------
__global__ __launch_bounds__(256) void stdp_reduce1(
    const float* __restrict__ partial, float* __restrict__ tmp)
{
    const int t = blockIdx.x * 256 + threadIdx.x;  // 0..524287
    const int g = t >> 16;                         // 0..7
    const int e = t & 65535;
    const int pt = e >> 15;
    const float* src = partial + ((size_t)(pt * 128 + g * 16)) * 32768 + (e & 32767);
    float a4[4] = {};
#pragma unroll
    for (int i = 0; i < 4; ++i)
#pragma unroll
        for (int u = 0; u < 4; ++u)
            a4[u] += src[(size_t)(u * 4 + i) * 32768];
    tmp[t] = (a4[0] + a4[1]) + (a4[2] + a4[3]);
}

// ---------------------------------------------------------------------------
// Reduce stage 2: 8 -> 1, scale by (A+ - A-)/(B*T).
// ---------------------------------------------------------------------------
__global__ __launch_bounds__(256) void stdp_reduce2(
    const float* __restrict__ tmp, float* __restrict__ out)
{
    const int idx = blockIdx.x * 256 + threadIdx.x;  // 0..65535
    float a[4];
#pragma unroll
    for (int u = 0; u < 4; ++u)
        a[u] = tmp[(size_t)(2 * u) * 65536 + idx] +
               tmp[(size_t)(2 * u + 1) * 65536 + idx];
    const float scale = (0.005f - 0.00525f) * (1.0f / (float)KTOT);
    out[idx] = ((a[0] + a[1]) + (a[2] + a[3])) * scale;
}

// ---------------------------------------------------------------------------
extern "C" void kernel_launch(void* const* d_in, const int* in_sizes, int n_in,
                              void* d_out, int out_size, void* d_ws, size_t ws_size,
                              hipStream_t stream)
{
    const float* pre  = (const float*)d_in[0];   // [512,100,256]
    const float* post = (const float*)d_in[1];   // [512,100,256]
    float* out = (float*)d_out;                  // [256,256]

    // ws: partial 33.5 MB | tmp 2 MB
    float* partial = (float*)d_ws;
    float* tmp     = (float*)((char*)d_ws + (size_t)33554432);

    stdp_fused_gemm<<<256, 512, 0, stream>>>(pre, post, partial);
    stdp_reduce1<<<2048, 256, 0, stream>>>(partial, tmp);
    stdp_reduce2<<<256, 256, 0, stream>>>(tmp, out);
}

// Round 10
// 166.112 us; speedup vs baseline: 1.0703x; 1.0703x over previous
//
#include <hip/hip_runtime.h>
#include <stdint.h>

// Problem constants (from reference)
#define B_SZ   512
#define T_SZ   100
#define NPRE   256
#define NPOST  256
#define KTOT   (B_SZ * T_SZ)   // 51200

typedef __bf16 bf16x8 __attribute__((ext_vector_type(8)));
typedef float  floatx4 __attribute__((ext_vector_type(4)));

__device__ __forceinline__ uint32_t bf16_rne(float v) {
    uint32_t bits = __float_as_uint(v);
    return (bits + 0x7FFFu + ((bits >> 16) & 1u)) >> 16;
}
__device__ __forceinline__ uint32_t pack_trunc2(float a, float b) {
    return (__float_as_uint(a) >> 16) | (__float_as_uint(b) & 0xFFFF0000u);
}

// ---------------------------------------------------------------------------
// Fused scan+GEMM: 512 blocks x 512 thr.  s = bx&127 (batches 4s..4s+3),
// tile = bx>>7: pt = tile&1 (p half), qt = tile>>1 (q half).
// Tile 128p x 128q -> acc[2][4] = 32 AGPR; LDS A 32 KB + B 32 KB + 1 KB
// carry = 65 KB -> 2 blocks/CU (the R8 latency fix WITHOUT the R9 spill:
// peak regs ~110 <= 128).
// XCD pairing is automatic: blocks sharing post differ by 128, sharing pre
// by 256 -> same XCD (mod 8), re-reads hit L2.
//
// Scan (per round r of 2): 512 threads = 2 batches x 128 p x 2 t-halves.
//   h0: sequential fp32 scan t0..63 -> pk[32] (bit-identical to reference
//       recurrence + RNE bf16).
//   h1: zero-carry scan t64..99 -> ze[36], then after LDS carry exchange
//       corrects trace_t = z_t + c64*d^(t-64) (exact by linearity; fp32
//       rounding diff negligible vs bf16 quantization).
// Per batch lb: matching quarter deposits A_lds fragment lines; all threads
// stage post->B_lds (flat unconditional batched loads); sync; 4 kc MFMA; sync.
// ---------------------------------------------------------------------------
__global__ __launch_bounds__(512, 4) void stdp_fused_gemm(
    const float* __restrict__ pre, const float* __restrict__ post,
    float* __restrict__ partial)
{
    __shared__ __align__(16) unsigned short A_lds[32][512];  // 32 KB
    __shared__ __align__(16) unsigned short B_lds[32][512];  // 32 KB
    __shared__ float carry_s[256];                           // 1 KB

    const int bx   = blockIdx.x;      // 0..511
    const int s    = bx & 127;
    const int tile = bx >> 7;         // 0..3
    const int pt   = tile & 1;
    const int qt   = tile >> 1;
    const int tid  = threadIdx.x;
    const int lane = tid & 63, wave = tid >> 6;
    const int wp = wave & 3, wq = wave >> 2;       // 32p x 64q wave region
    const int l15 = lane & 15, l4 = lane >> 4;

    const int task = tid & 255;       // (lbq, p_loc)
    const int lbq  = task >> 7;       // which of the round's 2 batches (wave-uniform)
    const int p_loc = task & 127;
    const int hf   = tid >> 8;        // t-half (wave-uniform)

    const int qq  = tid & 127;        // B-staging column
    const int th  = (tid >> 7) & 3;   // B-staging kc (wave-uniform)
    const int qg  = qq >> 4, q15 = qq & 15;

    const float decay = 0.95122942450071400910f;   // expf(-1/20)

    floatx4 acc[2][4] = {};

    for (int r = 0; r < 2; ++r) {
        // ================= scan round r: batches 4s+2r, 4s+2r+1 =============
        uint32_t pk[32];
        float ze[36];
        {
            const int b = s * 4 + 2 * r + lbq;
            const float* src = pre + (size_t)b * (T_SZ * NPRE) + pt * 128 + p_loc;
            if (hf == 0) {
                float carry = 0.0f;
#pragma unroll
                for (int rr = 0; rr < 4; ++rr) {
                    float x[16];
#pragma unroll
                    for (int j = 0; j < 16; ++j)
                        x[j] = src[(size_t)(rr * 16 + j) * NPRE];
#pragma unroll
                    for (int j = 0; j < 8; ++j) {
                        uint32_t lo = bf16_rne(carry);  // emit trace[t]=carry
                        carry = decay * (carry + x[2 * j]);
                        uint32_t hi = bf16_rne(carry);
                        carry = decay * (carry + x[2 * j + 1]);
                        pk[rr * 8 + j] = lo | (hi << 16);
                    }
                }
                carry_s[task] = carry;   // = trace[64]
            } else {
                float z = 0.0f;
#pragma unroll
                for (int rr = 0; rr < 2; ++rr) {
                    float x[16];
#pragma unroll
                    for (int j = 0; j < 16; ++j)
                        x[j] = src[(size_t)(64 + rr * 16 + j) * NPRE];
#pragma unroll
                    for (int j = 0; j < 16; ++j) {
                        ze[rr * 16 + j] = z;
                        z = decay * (z + x[j]);
                    }
                }
                {
                    float x[4];
#pragma unroll
                    for (int j = 0; j < 4; ++j)
                        x[j] = src[(size_t)(96 + j) * NPRE];
#pragma unroll
                    for (int j = 0; j < 4; ++j) {
                        ze[32 + j] = z;
                        z = decay * (z + x[j]);
                    }
                }
            }
        }
        __syncthreads();   // carry exchange
        if (hf == 1) {
            float c = carry_s[task];
            float pw = 1.0f;
#pragma unroll
            for (int j = 0; j < 18; ++j) {
                uint32_t lo = bf16_rne(ze[2 * j] + c * pw);      pw *= decay;
                uint32_t hi = bf16_rne(ze[2 * j + 1] + c * pw);  pw *= decay;
                pk[j] = lo | (hi << 16);
            }
        }

        // ================= lb loop: the round's 2 batches ====================
        for (int lh = 0; lh < 2; ++lh) {
            const int lb = 2 * r + lh;

            if (lbq == lh) {  // deposit this batch's A fragment lines
                const int pg = p_loc >> 4, lp = p_loc & 15;
                if (hf == 0) {
                    // kc 0,1 (t 0..63)
#pragma unroll
                    for (int kc = 0; kc < 2; ++kc)
#pragma unroll
                        for (int w = 0; w < 4; ++w)
                            *(uint4*)&A_lds[kc * 8 + pg][(w * 16 + lp) * 8] =
                                make_uint4(pk[kc * 16 + w * 4],     pk[kc * 16 + w * 4 + 1],
                                           pk[kc * 16 + w * 4 + 2], pk[kc * 16 + w * 4 + 3]);
                } else {
                    // kc 2 (t 64..95)
#pragma unroll
                    for (int w = 0; w < 4; ++w)
                        *(uint4*)&A_lds[16 + pg][(w * 16 + lp) * 8] =
                            make_uint4(pk[w * 4], pk[w * 4 + 1],
                                       pk[w * 4 + 2], pk[w * 4 + 3]);
                    // kc 3 (t 96..99 real, 100..127 zero)
                    *(uint4*)&A_lds[24 + pg][lp * 8] =
                        make_uint4(pk[16], pk[17], 0u, 0u);
#pragma unroll
                    for (int w = 1; w < 4; ++w)
                        *(uint4*)&A_lds[24 + pg][(w * 16 + lp) * 8] =
                            make_uint4(0u, 0u, 0u, 0u);
                }
            }

            // ---- B staging: thread (qq, th) covers kc=th for its column ----
            const float* pb = post + (size_t)(s * 4 + lb) * (T_SZ * NPOST) + qt * 128 + qq;
            if (th < 3) {
#pragma unroll
                for (int rr = 0; rr < 2; ++rr) {
                    float x[16];
#pragma unroll
                    for (int j = 0; j < 16; ++j)
                        x[j] = pb[(size_t)(th * 32 + rr * 16 + j) * NPOST];
#pragma unroll
                    for (int o = 0; o < 2; ++o)
                        *(uint4*)&B_lds[th * 8 + qg][((rr * 2 + o) * 16 + q15) * 8] =
                            make_uint4(pack_trunc2(x[o * 8 + 0], x[o * 8 + 1]),
                                       pack_trunc2(x[o * 8 + 2], x[o * 8 + 3]),
                                       pack_trunc2(x[o * 8 + 4], x[o * 8 + 5]),
                                       pack_trunc2(x[o * 8 + 6], x[o * 8 + 7]));
                }
            } else {
                float y[4];
#pragma unroll
                for (int j = 0; j < 4; ++j)
                    y[j] = pb[(size_t)(96 + j) * NPOST];
                *(uint4*)&B_lds[24 + qg][q15 * 8] =
                    make_uint4(pack_trunc2(y[0], y[1]), pack_trunc2(y[2], y[3]), 0u, 0u);
#pragma unroll
                for (int o = 1; o < 4; ++o)
                    *(uint4*)&B_lds[24 + qg][(o * 16 + q15) * 8] =
                        make_uint4(0u, 0u, 0u, 0u);
            }
            __syncthreads();

            // ---- MFMA: 4 chunks of K=32
#pragma unroll
            for (int kc = 0; kc < 4; ++kc) {
                bf16x8 a[2], bb[4];
#pragma unroll
                for (int f = 0; f < 2; ++f)
                    a[f] = *(const bf16x8*)&A_lds[kc * 8 + wp * 2 + f][lane * 8];
#pragma unroll
                for (int g = 0; g < 4; ++g)
                    bb[g] = *(const bf16x8*)&B_lds[kc * 8 + wq * 4 + g][lane * 8];
#pragma unroll
                for (int f = 0; f < 2; ++f)
#pragma unroll
                    for (int g = 0; g < 4; ++g)
                        acc[f][g] = __builtin_amdgcn_mfma_f32_16x16x32_bf16(
                            a[f], bb[g], acc[f][g], 0, 0, 0);
            }
            __syncthreads();
        }
    }

    // ---- writeout: partial[bx][p_loc 128][q_loc 128]
    // C/D layout (m89/m91): col = lane&15, row = (lane>>4)*4 + reg
    float* pout = partial + (size_t)bx * (128 * 128);
#pragma unroll
    for (int f = 0; f < 2; ++f) {
        int r0 = wp * 32 + f * 16 + l4 * 4;
#pragma unroll
        for (int g = 0; g < 4; ++g) {
            int c = wq * 64 + g * 16 + l15;
#pragma unroll
            for (int v = 0; v < 4; ++v)
                pout[(size_t)(r0 + v) * 128 + c] = acc[f][g][v];
        }
    }
}

// ---------------------------------------------------------------------------
// Reduce stage 1: partial[bx = tile*128 + s][i], i = p_loc*128+q_loc.
// 2048 blocks x 256 thr; thread t: g = t>>16 (0..7), e = t&65535,
// tile = e>>14, i = e&16383; sums s = g*16..+15 (4 indep chains).
// ---------------------------------------------------------------------------
__global__ __launch_bounds__(256) void stdp_reduce1(
    const float* __restrict__ partial, float* __restrict__ tmp)
{
    const int t = blockIdx.x * 256 + threadIdx.x;  // 0..524287
    const int g = t >> 16;                         // 0..7
    const int e = t & 65535;
    const int tile = e >> 14;
    const float* src = partial + ((size_t)(tile * 128 + g * 16) << 14) + (e & 16383);
    float a4[4] = {};
#pragma unroll
    for (int i = 0; i < 4; ++i)
#pragma unroll
        for (int u = 0; u < 4; ++u)
            a4[u] += src[(size_t)(u * 4 + i) << 14];
    tmp[t] = (a4[0] + a4[1]) + (a4[2] + a4[3]);
}

// ---------------------------------------------------------------------------
// Reduce stage 2: 8 -> 1, un-tile, scale by (A+ - A-)/(B*T).
// ---------------------------------------------------------------------------
__global__ __launch_bounds__(256) void stdp_reduce2(
    const float* __restrict__ tmp, float* __restrict__ out)
{
    const int idx = blockIdx.x * 256 + threadIdx.x;  // 0..65535
    const int P = idx >> 8, Q = idx & 255;
    const int tile = (Q >> 7) * 2 + (P >> 7);
    const int e = (tile << 14) | ((P & 127) << 7) | (Q & 127);
    float a[4];
#pragma unroll
    for (int u = 0; u < 4; ++u)
        a[u] = tmp[(size_t)(2 * u) * 65536 + e] +
               tmp[(size_t)(2 * u + 1) * 65536 + e];
    const float scale = (0.005f - 0.00525f) * (1.0f / (float)KTOT);
    out[idx] = ((a[0] + a[1]) + (a[2] + a[3])) * scale;
}

// ---------------------------------------------------------------------------
extern "C" void kernel_launch(void* const* d_in, const int* in_sizes, int n_in,
                              void* d_out, int out_size, void* d_ws, size_t ws_size,
                              hipStream_t stream)
{
    const float* pre  = (const float*)d_in[0];   // [512,100,256]
    const float* post = (const float*)d_in[1];   // [512,100,256]
    float* out = (float*)d_out;                  // [256,256]

    // ws: partial 33.5 MB | tmp 2 MB
    float* partial = (float*)d_ws;
    float* tmp     = (float*)((char*)d_ws + (size_t)33554432);

    stdp_fused_gemm<<<512, 512, 0, stream>>>(pre, post, partial);
    stdp_reduce1<<<2048, 256, 0, stream>>>(partial, tmp);
    stdp_reduce2<<<256, 256, 0, stream>>>(tmp, out);
}

// Round 12
// 142.185 us; speedup vs baseline: 1.2504x; 1.1683x over previous
//
#include <hip/hip_runtime.h>
#include <stdint.h>

// Problem constants (from reference)
#define B_SZ   512
#define T_SZ   100
#define NPRE   256
#define NPOST  256
#define KTOT   (B_SZ * T_SZ)   // 51200

typedef __bf16 bf16x8 __attribute__((ext_vector_type(8)));
typedef float  floatx4 __attribute__((ext_vector_type(4)));

__device__ __forceinline__ uint32_t bf16_rne(float v) {
    uint32_t bits = __float_as_uint(v);
    return (bits + 0x7FFFu + ((bits >> 16) & 1u)) >> 16;
}
__device__ __forceinline__ uint32_t pack_trunc2(float a, float b) {
    return (__float_as_uint(a) >> 16) | (__float_as_uint(b) & 0xFFFF0000u);
}

// ---------------------------------------------------------------------------
// Fused scan+GEMM: 512 blocks x 256 thr (4 waves).  s = bx&127 (batches
// 4s..4s+3), tile = bx>>7: pt = tile&1 (p half), qt = tile>>1 (q half);
// tile 128p x 128q (R10-proven mapping & reduce layout).
// LDS = A 32 KB + B 32 KB = 64 KB and __launch_bounds__(256,2) (256-reg
// budget, peak ~190 -> no spill) => 2 blocks/CU: one block's barrier drain
// overlaps the other block's loads/MFMA (m114) — the R8 latency fix without
// R9/R10's spill or R11's LDS overflow.
// All 4 quadrant blocks of split s are == s (mod 8) -> same XCD; pre/post
// re-reads served from L2.
//
// Scan: 2 rounds x 2 batches (256 thr = 2 batches x 128 p), R8's bit-exact
// sequential fp32 scan + RNE->bf16, pk[50].
// Per batch: half (lbq==lh) deposits A fragment lines; all threads stage
// post -> B_lds (flat unconditional batched loads, trunc exact for {0,1});
// sync; 4 kc x 16 MFMA; sync.
// ---------------------------------------------------------------------------
__global__ __launch_bounds__(256, 2) void stdp_fused_gemm(
    const float* __restrict__ pre, const float* __restrict__ post,
    float* __restrict__ partial)
{
    __shared__ __align__(16) unsigned short A_lds[32][512];  // 32 KB
    __shared__ __align__(16) unsigned short B_lds[32][512];  // 32 KB

    const int bx   = blockIdx.x;      // 0..511
    const int s    = bx & 127;
    const int tile = bx >> 7;         // 0..3
    const int pt   = tile & 1;
    const int qt   = tile >> 1;
    const int tid  = threadIdx.x;     // 0..255
    const int lane = tid & 63, wave = tid >> 6;   // wave = wp (0..3)
    const int l15 = lane & 15, l4 = lane >> 4;

    const int half  = tid >> 7;       // 0/1 (wave-uniform): scan batch / B t-half
    const int p_loc = tid & 127;      // scan row
    const int qloc  = tid & 127;      // B column
    const int qg = qloc >> 4, q15 = qloc & 15;

    const float decay = 0.95122942450071400910f;   // expf(-1/20)

    floatx4 acc[2][8] = {};

    for (int r = 0; r < 2; ++r) {
        // ---- scan round r: batches 4s+2r+{0,1}; this thread scans one ----
        uint32_t pk[50];
        {
            const int b = s * 4 + 2 * r + half;
            const float* src = pre + (size_t)b * (T_SZ * NPRE) + pt * 128 + p_loc;
            float carry = 0.0f;
#pragma unroll
            for (int kc = 0; kc < 3; ++kc) {
                float x[32];
#pragma unroll
                for (int j = 0; j < 32; ++j)
                    x[j] = src[(size_t)(kc * 32 + j) * NPRE];
#pragma unroll
                for (int j = 0; j < 16; ++j) {
                    uint32_t lo = bf16_rne(carry);   // trace[t]=carry, then update
                    carry = decay * (carry + x[2 * j]);
                    uint32_t hi = bf16_rne(carry);
                    carry = decay * (carry + x[2 * j + 1]);
                    pk[kc * 16 + j] = lo | (hi << 16);
                }
            }
            float x[4];
#pragma unroll
            for (int j = 0; j < 4; ++j)
                x[j] = src[(size_t)(96 + j) * NPRE];
#pragma unroll
            for (int j = 0; j < 2; ++j) {
                uint32_t lo = bf16_rne(carry);
                carry = decay * (carry + x[2 * j]);
                uint32_t hi = bf16_rne(carry);
                carry = decay * (carry + x[2 * j + 1]);
                pk[48 + j] = lo | (hi << 16);
            }
        }

        // ---- the round's 2 batches ----
        for (int lh = 0; lh < 2; ++lh) {
            const int b = s * 4 + 2 * r + lh;

            if (half == lh) {
                // deposit trace into A_lds fragment lines:
                // line kc*8+pg, slot w*16+lp holds t = kc*32 + w*8 .. +7
                const int pg = p_loc >> 4, lp = p_loc & 15;
#pragma unroll
                for (int kc = 0; kc < 3; ++kc)
#pragma unroll
                    for (int w = 0; w < 4; ++w)
                        *(uint4*)&A_lds[kc * 8 + pg][(w * 16 + lp) * 8] =
                            make_uint4(pk[kc * 16 + w * 4],     pk[kc * 16 + w * 4 + 1],
                                       pk[kc * 16 + w * 4 + 2], pk[kc * 16 + w * 4 + 3]);
                // kc = 3: t 96..99 real, 100..127 zero
                *(uint4*)&A_lds[24 + pg][lp * 8] = make_uint4(pk[48], pk[49], 0u, 0u);
#pragma unroll
                for (int w = 1; w < 4; ++w)
                    *(uint4*)&A_lds[24 + pg][(w * 16 + lp) * 8] =
                        make_uint4(0u, 0u, 0u, 0u);
            }

            // ---- B staging: flat unconditional batched loads ----
            // thread (qloc, half): half=0 -> t 0..47, half=1 -> t 48..99(+pad)
            const float* pb = post + (size_t)b * (T_SZ * NPOST) + qt * 128 + qloc;
            if (half == 0) {
                float x[48];
#pragma unroll
                for (int j = 0; j < 48; ++j)
                    x[j] = pb[(size_t)j * NPOST];
#pragma unroll
                for (int o = 0; o < 6; ++o)   // octs 0..5: t 0..47
                    *(uint4*)&B_lds[(o >> 2) * 8 + qg][((o & 3) * 16 + q15) * 8] =
                        make_uint4(pack_trunc2(x[o * 8 + 0], x[o * 8 + 1]),
                                   pack_trunc2(x[o * 8 + 2], x[o * 8 + 3]),
                                   pack_trunc2(x[o * 8 + 4], x[o * 8 + 5]),
                                   pack_trunc2(x[o * 8 + 6], x[o * 8 + 7]));
            } else {
                float x[52];
#pragma unroll
                for (int j = 0; j < 52; ++j)
                    x[j] = pb[(size_t)(48 + j) * NPOST];
#pragma unroll
                for (int o = 6; o < 12; ++o) {  // octs 6..11: t 48..95
                    int u = o * 8 - 48;
                    *(uint4*)&B_lds[(o >> 2) * 8 + qg][((o & 3) * 16 + q15) * 8] =
                        make_uint4(pack_trunc2(x[u + 0], x[u + 1]),
                                   pack_trunc2(x[u + 2], x[u + 3]),
                                   pack_trunc2(x[u + 4], x[u + 5]),
                                   pack_trunc2(x[u + 6], x[u + 7]));
                }
                // oct 12: t 96..99 real + zeros; octs 13..15: zero
                *(uint4*)&B_lds[24 + qg][q15 * 8] =
                    make_uint4(pack_trunc2(x[48], x[49]), pack_trunc2(x[50], x[51]), 0u, 0u);
#pragma unroll
                for (int o = 13; o < 16; ++o)
                    *(uint4*)&B_lds[24 + qg][((o & 3) * 16 + q15) * 8] =
                        make_uint4(0u, 0u, 0u, 0u);
            }
            __syncthreads();

            // ---- MFMA: 4 chunks of K=32; wave wp covers 32p x 128q ----
#pragma unroll
            for (int kc = 0; kc < 4; ++kc) {
                bf16x8 a[2], bb[8];
#pragma unroll
                for (int f = 0; f < 2; ++f)
                    a[f] = *(const bf16x8*)&A_lds[kc * 8 + wave * 2 + f][lane * 8];
#pragma unroll
                for (int g = 0; g < 8; ++g)
                    bb[g] = *(const bf16x8*)&B_lds[kc * 8 + g][lane * 8];
#pragma unroll
                for (int f = 0; f < 2; ++f)
#pragma unroll
                    for (int g = 0; g < 8; ++g)
                        acc[f][g] = __builtin_amdgcn_mfma_f32_16x16x32_bf16(
                            a[f], bb[g], acc[f][g], 0, 0, 0);
            }
            __syncthreads();
        }
    }

    // ---- writeout: partial[bx][p_loc 128][q_loc 128]
    // C/D layout (m89/m91): col = lane&15, row = (lane>>4)*4 + reg
    float* pout = partial + (size_t)bx * (128 * 128);
#pragma unroll
    for (int f = 0; f < 2; ++f) {
        int r0 = wave * 32 + f * 16 + l4 * 4;
#pragma unroll
        for (int g = 0; g < 8; ++g) {
            int c = g * 16 + l15;
#pragma unroll
            for (int v = 0; v < 4; ++v)
                pout[(size_t)(r0 + v) * 128 + c] = acc[f][g][v];
        }
    }
}

// ---------------------------------------------------------------------------
// Reduce stage 1 (R10-proven): partial[bx = tile*128 + s][i], i = p*128+q.
// 2048 blocks x 256 thr; thread t: g = t>>16 (0..7), e = t&65535,
// tile = e>>14; sums s = g*16..+15 (4 indep chains).
// ---------------------------------------------------------------------------
__global__ __launch_bounds__(256) void stdp_reduce1(
    const float* __restrict__ partial, float* __restrict__ tmp)
{
    const int t = blockIdx.x * 256 + threadIdx.x;  // 0..524287
    const int g = t >> 16;                         // 0..7
    const int e = t & 65535;
    const int tile = e >> 14;
    const float* src = partial + ((size_t)(tile * 128 + g * 16) << 14) + (e & 16383);
    float a4[4] = {};
#pragma unroll
    for (int i = 0; i < 4; ++i)
#pragma unroll
        for (int u = 0; u < 4; ++u)
            a4[u] += src[(size_t)(u * 4 + i) << 14];
    tmp[t] = (a4[0] + a4[1]) + (a4[2] + a4[3]);
}

// ---------------------------------------------------------------------------
// Reduce stage 2 (R10-proven): 8 -> 1, un-tile, scale by (A+ - A-)/(B*T).
// ---------------------------------------------------------------------------
__global__ __launch_bounds__(256) void stdp_reduce2(
    const float* __restrict__ tmp, float* __restrict__ out)
{
    const int idx = blockIdx.x * 256 + threadIdx.x;  // 0..65535
    const int P = idx >> 8, Q = idx & 255;
    const int tile = (Q >> 7) * 2 + (P >> 7);
    const int e = (tile << 14) | ((P & 127) << 7) | (Q & 127);
    float a[4];
#pragma unroll
    for (int u = 0; u < 4; ++u)
        a[u] = tmp[(size_t)(2 * u) * 65536 + e] +
               tmp[(size_t)(2 * u + 1) * 65536 + e];
    const float scale = (0.005f - 0.00525f) * (1.0f / (float)KTOT);
    out[idx] = ((a[0] + a[1]) + (a[2] + a[3])) * scale;
}

// ---------------------------------------------------------------------------
extern "C" void kernel_launch(void* const* d_in, const int* in_sizes, int n_in,
                              void* d_out, int out_size, void* d_ws, size_t ws_size,
                              hipStream_t stream)
{
    const float* pre  = (const float*)d_in[0];   // [512,100,256]
    const float* post = (const float*)d_in[1];   // [512,100,256]
    float* out = (float*)d_out;                  // [256,256]

    // ws: partial 33.5 MB | tmp 2 MB
    float* partial = (float*)d_ws;
    float* tmp     = (float*)((char*)d_ws + (size_t)33554432);

    stdp_fused_gemm<<<512, 256, 0, stream>>>(pre, post, partial);
    stdp_reduce1<<<2048, 256, 0, stream>>>(partial, tmp);
    stdp_reduce2<<<256, 256, 0, stream>>>(tmp, out);
}